// Round 4
// baseline (212.450 us; speedup 1.0000x reference)
//
#include <hip/hip_runtime.h>

// LSTMClassifier: B=4096, T=128, I=32, H=64, 2-layer LSTM + MLP head.
// Round 4: layer-pipelined persistent blocks, double-buffered LDS h-state,
// ONE barrier per timestep. 256 blocks x 512 threads (8 waves): waves 0-3
// layer 0 at step k, waves 4-7 layer 1 at step k-1. Weights persist in
// per-wave MFMA B-fragments. x A-fragments load DIRECTLY global->reg with
// 2-step lookahead (no LDS staging). f16 MFMA operands, fp32 state.

#define TT 128
#define II 32
#define HH 64

typedef _Float16 half8 __attribute__((ext_vector_type(8)));
typedef float floatx4 __attribute__((ext_vector_type(4)));

#define LOG2E 1.4426950408889634f

// Load 8 consecutive fp32 of row n (K-major) and convert to an f16 MFMA fragment.
__device__ __forceinline__ half8 load_w_frag(const float* __restrict__ W, int n, int K, int k0) {
    const float* p = W + (size_t)n * K + k0;
    float4 a = *(const float4*)p;
    float4 b = *(const float4*)(p + 4);
    half8 h;
    h[0] = (_Float16)a.x; h[1] = (_Float16)a.y; h[2] = (_Float16)a.z; h[3] = (_Float16)a.w;
    h[4] = (_Float16)b.x; h[5] = (_Float16)b.y; h[6] = (_Float16)b.z; h[7] = (_Float16)b.w;
    return h;
}

__device__ __forceinline__ half8 cvt_frag(float4 a, float4 b) {
    half8 h;
    h[0] = (_Float16)a.x; h[1] = (_Float16)a.y; h[2] = (_Float16)a.z; h[3] = (_Float16)a.w;
    h[4] = (_Float16)b.x; h[5] = (_Float16)b.y; h[6] = (_Float16)b.z; h[7] = (_Float16)b.w;
    return h;
}

// sigma(a)*tanh(b) = (e^{2b}-1)/((1+e^{-a})(e^{2b}+1)).
// Unclamped: valid while |b| < 44 (gate pre-activations bounded ~30).
__device__ __forceinline__ float sig_tanh_nc(float a, float b) {
    float u  = __builtin_amdgcn_exp2f(b * (2.0f * LOG2E));
    float v  = __builtin_amdgcn_exp2f(-a * LOG2E);
    float num = u - 1.0f;
    float d1  = u + 1.0f;
    float den = fmaf(v, d1, d1);          // (1+v)*(u+1)
    return num * __builtin_amdgcn_rcpf(den);
}
// Clamped variant for b = cell state c (can accumulate over 128 steps).
__device__ __forceinline__ float sig_tanh_cl(float a, float b) {
    float bb = fminf(fmaxf(b, -15.f), 15.f);
    return sig_tanh_nc(a, bb);
}
__device__ __forceinline__ float fsig(float x) {
    return __builtin_amdgcn_rcpf(1.0f + __builtin_amdgcn_exp2f(-x * LOG2E));
}

__global__ __launch_bounds__(512, 2) void lstm_fused(
    const float* __restrict__ x,
    const float* __restrict__ Wih0, const float* __restrict__ Whh0,
    const float* __restrict__ bih0, const float* __restrict__ bhh0,
    const float* __restrict__ Wih1, const float* __restrict__ Whh1,
    const float* __restrict__ bih1, const float* __restrict__ bhh1,
    const float* __restrict__ Wc1, const float* __restrict__ bc1,
    const float* __restrict__ Wc2, const float* __restrict__ bc2,
    float* __restrict__ out)
{
    // Double-buffered h state; +8 f16 padding keeps 16B alignment (stride
    // 144B) with only 2-way bank aliasing on b128 reads (free per m136).
    __shared__ __align__(16) _Float16 h0s[2][16][72];
    __shared__ __align__(16) _Float16 h1s[2][16][72];
    __shared__ __align__(16) float h1f[16][68];   // final-step h1 (fp32)
    __shared__ float hid[16][32];

    const int tid  = threadIdx.x;
    const int wid  = tid >> 6;        // wave 0..7
    const int w4   = wid & 3;         // gate-column group within the layer
    const bool isL0 = (wid < 4);
    const int lane = tid & 63;
    const int q  = lane >> 4;         // quad 0..3
    const int lr = lane & 15;
    const int b0 = blockIdx.x * 16;

    // ---- persistent weight fragments (registers, whole kernel) ----
    // Wave group w4 owns gate-column tiles n = (w4 + 4g)*16, g in {i,f,g,o}:
    // all four gates for channels [16*w4, 16*w4+16) are lane-local at eltwise.
    // B-frag: lane holds B[k][n], n = tile + lr, k = 8q + j; B = W^T so the
    // lane reads W[n][8q..8q+8) contiguously.
    half8 bx0[4], bh0[4][2];          // layer-0 waves
    half8 bi1[4][2], bh1[4][2];       // layer-1 waves
    float biasv[4];
    if (isL0) {
        #pragma unroll
        for (int g = 0; g < 4; ++g) {
            int n = (w4 + 4 * g) * 16 + lr;
            bx0[g]    = load_w_frag(Wih0, n, 32, q * 8);
            bh0[g][0] = load_w_frag(Whh0, n, 64, q * 8);
            bh0[g][1] = load_w_frag(Whh0, n, 64, 32 + q * 8);
            biasv[g]  = bih0[n] + bhh0[n];
        }
    } else {
        #pragma unroll
        for (int g = 0; g < 4; ++g) {
            int n = (w4 + 4 * g) * 16 + lr;
            bi1[g][0] = load_w_frag(Wih1, n, 64, q * 8);
            bi1[g][1] = load_w_frag(Wih1, n, 64, 32 + q * 8);
            bh1[g][0] = load_w_frag(Whh1, n, 64, q * 8);
            bh1[g][1] = load_w_frag(Whh1, n, 64, 32 + q * 8);
            biasv[g]  = bih1[n] + bhh1[n];
        }
    }

    // zero-init both h-state buffers (h0(-1) = h1(-1) = h1(-2) = 0)
    for (int i = tid; i < 2 * 16 * 72; i += 512) {
        ((_Float16*)h0s)[i] = (_Float16)0.0f;
        ((_Float16*)h1s)[i] = (_Float16)0.0f;
    }

    float cr[4] = {0.f, 0.f, 0.f, 0.f};   // c state for this wave's layer

    // ---- direct global->reg x A-fragments (L0 waves), 2-step lookahead ----
    // Lane (q,lr) needs x[b0+lr][t][8q..8q+8): 32B/lane; lanes sharing lr
    // cover one aligned 128B row-step segment -> 16 segments per wave.
    const float* xlane = x + ((size_t)(b0 + lr) * TT) * II + q * 8;
    half8 xfrag_cur;                   // f16 frag for step k
    float4 xra, xrb;                   // raw fp32 for step k+1
    if (isL0) {
        float4 a0 = *(const float4*)(xlane);
        float4 b0f = *(const float4*)(xlane + 4);
        xfrag_cur = cvt_frag(a0, b0f);                 // x(0)
        xra = *(const float4*)(xlane + II);            // x(1)
        xrb = *(const float4*)(xlane + II + 4);
    }

    // Iteration k: waves 0-3 compute h0(k) (k < TT); waves 4-7 compute h1(k-1)
    // (k >= 1). h*(k) -> buf[k&1]; h*(k-1) read from buf[(k+1)&1].
    // Single barrier per iter: read- and write-buffers never alias, and writes
    // to a buffer are separated from its readers by the next barrier.
    #pragma unroll 2
    for (int k = 0; k <= TT; ++k) {
        __syncthreads();

        const int rd = (k + 1) & 1;
        const int wr = k & 1;
        const bool doL0 = isL0 && (k < TT);
        const bool doL1 = (!isL0) && (k >= 1);
        float hnew[4];

        if (doL0) {
            // gates = bias0 + x(k) Wih0^T + h0(k-1) Whh0^T
            half8 h0a = *(const half8*)&h0s[rd][lr][q * 8];
            half8 h0b = *(const half8*)&h0s[rd][lr][32 + q * 8];
            // rotate x pipeline: frag for k+1, issue loads for k+2
            half8 xfrag_nxt = cvt_frag(xra, xrb);
            int t2 = (k + 2 < TT) ? (k + 2) : (TT - 1);
            xra = *(const float4*)(xlane + (size_t)t2 * II);
            xrb = *(const float4*)(xlane + (size_t)t2 * II + 4);
            floatx4 a0[4];
            #pragma unroll
            for (int g = 0; g < 4; ++g) {
                floatx4 acc = {biasv[g], biasv[g], biasv[g], biasv[g]};
                acc = __builtin_amdgcn_mfma_f32_16x16x32_f16(xfrag_cur, bx0[g],    acc, 0, 0, 0);
                acc = __builtin_amdgcn_mfma_f32_16x16x32_f16(h0a,       bh0[g][0], acc, 0, 0, 0);
                acc = __builtin_amdgcn_mfma_f32_16x16x32_f16(h0b,       bh0[g][1], acc, 0, 0, 0);
                a0[g] = acc;
            }
            xfrag_cur = xfrag_nxt;
            #pragma unroll
            for (int r = 0; r < 4; ++r) {
                float sf = fsig(a0[1][r]);
                float c  = fmaf(sf, cr[r], sig_tanh_nc(a0[0][r], a0[2][r]));
                cr[r] = c;
                hnew[r] = sig_tanh_cl(a0[3][r], c);
            }
        }
        if (doL1) {
            // gates = bias1 + h0(k-1) Wih1^T + h1(k-2) Whh1^T
            half8 g0a = *(const half8*)&h0s[rd][lr][q * 8];
            half8 g0b = *(const half8*)&h0s[rd][lr][32 + q * 8];
            half8 h1a = *(const half8*)&h1s[rd][lr][q * 8];
            half8 h1b = *(const half8*)&h1s[rd][lr][32 + q * 8];
            floatx4 a1[4];
            #pragma unroll
            for (int g = 0; g < 4; ++g) {
                floatx4 acc = {biasv[g], biasv[g], biasv[g], biasv[g]};
                acc = __builtin_amdgcn_mfma_f32_16x16x32_f16(g0a, bi1[g][0], acc, 0, 0, 0);
                acc = __builtin_amdgcn_mfma_f32_16x16x32_f16(g0b, bi1[g][1], acc, 0, 0, 0);
                acc = __builtin_amdgcn_mfma_f32_16x16x32_f16(h1a, bh1[g][0], acc, 0, 0, 0);
                acc = __builtin_amdgcn_mfma_f32_16x16x32_f16(h1b, bh1[g][1], acc, 0, 0, 0);
                a1[g] = acc;
            }
            #pragma unroll
            for (int r = 0; r < 4; ++r) {
                float sf = fsig(a1[1][r]);
                float c  = fmaf(sf, cr[r], sig_tanh_nc(a1[0][r], a1[2][r]));
                cr[r] = c;
                hnew[r] = sig_tanh_cl(a1[3][r], c);
            }
        }

        // writes go to buf[wr]; readers of buf[wr] are past the next barrier
        if (doL0) {
            #pragma unroll
            for (int r = 0; r < 4; ++r)
                h0s[wr][q * 4 + r][w4 * 16 + lr] = (_Float16)hnew[r];
        }
        if (doL1) {
            if (k == TT) {
                #pragma unroll
                for (int r = 0; r < 4; ++r)
                    h1f[q * 4 + r][w4 * 16 + lr] = hnew[r];
            } else {
                #pragma unroll
                for (int r = 0; r < 4; ++r)
                    h1s[wr][q * 4 + r][w4 * 16 + lr] = (_Float16)hnew[r];
            }
        }
    }
    __syncthreads();

    // ---- classifier (fp32): hidden = relu(hT Wc1^T + bc1); out = hidden Wc2^T + bc2
    if (tid < 256) {
        int m = tid >> 4;
        int u = (tid & 15) * 2;
        float a = bc1[u], b = bc1[u + 1];
        const float* w0 = Wc1 + u * 64;
        const float* w1 = Wc1 + (u + 1) * 64;
        #pragma unroll 8
        for (int kk = 0; kk < 64; ++kk) {
            float hv = h1f[m][kk];
            a += hv * w0[kk];
            b += hv * w1[kk];
        }
        hid[m][u]     = fmaxf(a, 0.f);
        hid[m][u + 1] = fmaxf(b, 0.f);
    }
    __syncthreads();
    if (tid < 16) {
        float o = bc2[0];
        #pragma unroll
        for (int u = 0; u < 32; ++u) o += hid[tid][u] * Wc2[u];
        out[b0 + tid] = o;
    }
}

extern "C" void kernel_launch(void* const* d_in, const int* in_sizes, int n_in,
                              void* d_out, int out_size, void* d_ws, size_t ws_size,
                              hipStream_t stream) {
    (void)in_sizes; (void)n_in; (void)d_ws; (void)ws_size; (void)out_size;
    const float* x    = (const float*)d_in[0];
    const float* Wih0 = (const float*)d_in[1];
    const float* Whh0 = (const float*)d_in[2];
    const float* bih0 = (const float*)d_in[3];
    const float* bhh0 = (const float*)d_in[4];
    const float* Wih1 = (const float*)d_in[5];
    const float* Whh1 = (const float*)d_in[6];
    const float* bih1 = (const float*)d_in[7];
    const float* bhh1 = (const float*)d_in[8];
    const float* Wc1  = (const float*)d_in[9];
    const float* bc1  = (const float*)d_in[10];
    const float* Wc2  = (const float*)d_in[11];
    const float* bc2  = (const float*)d_in[12];
    lstm_fused<<<dim3(256), dim3(512), 0, stream>>>(
        x, Wih0, Whh0, bih0, bhh0, Wih1, Whh1, bih1, bhh1, Wc1, bc1, Wc2, bc2,
        (float*)d_out);
}